// Round 9
// baseline (240.023 us; speedup 1.0000x reference)
//
#include <hip/hip_runtime.h>

// Box3dAttention: B=2, LQ=4096, d=256, heads=8, head_dim=32, 5x5=25 points,
// feature map 188x188 (LV=35344).
//
// Round 9 = round 8 + value-conversion fused into the value GEMM:
//  - gemm_mfma is now 512-thr, 128(M)x256(N) tile (grid.y=1 -> A read ONCE),
//    with A either fp32 (converted to bf16 in registers during LDS staging;
//    round-4 structure, exonerated) or bf16 (async16 direct-to-LDS).
//  - K0 converts weights only (49 blocks).
//  - Swapped-operand MFMA epilogue (verified in round 8): lane holds 4
//    consecutive n -> vectorized 8B/16B stores.
//
// Pipeline:
//  K0 convert_w : W_value/[W_attn;W_box]pad/W_out -> bf16, bias pad
//  K1 gemm<1,fp32A>: value @ W_value^T + b -> Vout bf16 head-major [b*8+h][LV][32]
//  K2 gemm_nt   : fp32 VALU logits = query @ [W_attn;W_box]^T + b (box accuracy)
//  K3 decode_sample: block=(slice s=b*8+h, 8 q); s fast grid dim -> XCD s%8
//  K4 gemm<0,bf16A>: ohbf @ wobf^T + b_out -> out fp32

typedef float floatx4 __attribute__((ext_vector_type(4)));
typedef short shortx8 __attribute__((ext_vector_type(8)));

static __device__ __forceinline__ unsigned short f2bf(float x) {
    unsigned int u = __float_as_uint(x);
    return (unsigned short)((u + 0x7fffu + ((u >> 16) & 1u)) >> 16);
}
static __device__ __forceinline__ unsigned int pack2(float a, float b) {
    return (unsigned int)f2bf(a) | ((unsigned int)f2bf(b) << 16);
}
static __device__ __forceinline__ void async16(const void* g, void* lds) {
    __builtin_amdgcn_global_load_lds(
        (const __attribute__((address_space(1))) unsigned int*)g,
        (__attribute__((address_space(3))) unsigned int*)lds, 16, 0, 0);
}

// ---------------- K0: weight conversions (49 blocks) ----------------
__global__ __launch_bounds__(256) void convert_w(
    const float* __restrict__ W_value, unsigned short* __restrict__ wvbf,
    const float* __restrict__ W_attn, const float* __restrict__ W_box,
    unsigned short* __restrict__ wabf, float* __restrict__ Wab,
    const float* __restrict__ W_out, unsigned short* __restrict__ wobf,
    const float* __restrict__ b_attn, const float* __restrict__ b_box,
    float* __restrict__ bab)
{
    const int blk = blockIdx.x, tid = threadIdx.x;
    if (blk < 16) {
        int base = blk * 1024 + tid;
#pragma unroll
        for (int k = 0; k < 4; ++k) {
            int j = base + k * 256;
            float4 f = ((const float4*)W_value)[j];
            ((uint2*)wvbf)[j] = make_uint2(pack2(f.x, f.y), pack2(f.z, f.w));
        }
    } else if (blk < 32) {
        int base = (blk - 16) * 1024 + tid;
#pragma unroll
        for (int k = 0; k < 4; ++k) {
            int j = base + k * 256;
            int row = j >> 6, col = (j & 63) * 4;
            float4 f;
            if (row < 200)      f = *(const float4*)(W_attn + (size_t)row * 256 + col);
            else if (row < 240) f = *(const float4*)(W_box + (size_t)(row - 200) * 256 + col);
            else                f = make_float4(0.f, 0.f, 0.f, 0.f);
            ((uint2*)wabf)[j] = make_uint2(pack2(f.x, f.y), pack2(f.z, f.w));
            ((float4*)Wab)[j] = f;
        }
    } else if (blk < 48) {
        int base = (blk - 32) * 1024 + tid;
#pragma unroll
        for (int k = 0; k < 4; ++k) {
            int j = base + k * 256;
            float4 f = ((const float4*)W_out)[j];
            ((uint2*)wobf)[j] = make_uint2(pack2(f.x, f.y), pack2(f.z, f.w));
        }
    } else {
        bab[tid] = tid < 200 ? b_attn[tid] : (tid < 240 ? b_box[tid - 200] : 0.f);
    }
}

// ---------------- unified bf16 MFMA GEMM, 128x256 tile, 512 thr ----------------
// C = A(M x 256) @ Bw(256 x 256 bf16)^T + bias
// AFP32 1: A fp32, converted to bf16 in registers during LDS staging.
// AFP32 0: A bf16, async16 direct-to-LDS.
// OUTMODE 0: C fp32 row-major [M][256]; OUTMODE 1: C bf16 head-major [b*8+h][LV][32]
// Swapped-operand MFMA (round-8 verified): lane holds 4 consecutive n.
template <int OUTMODE, int AFP32>
__global__ __launch_bounds__(512) void gemm_mfma(
    const void* __restrict__ Av,
    const unsigned short* __restrict__ Bw,
    const float* __restrict__ bias,
    void* __restrict__ Cv, int M, int LV)
{
    __shared__ unsigned short As[128 * 64];   // 16 KB
    __shared__ unsigned short Bs[256 * 64];   // 32 KB
    const int tid = threadIdx.x;
    const int wv = tid >> 6, lane = tid & 63;
    const int lr = lane & 15, lq = lane >> 4;
    const int wm = wv & 1, wn = wv >> 1;      // 2(m) x 4(n) wave grid
    const int m0 = blockIdx.x * 128;
    const int srow = tid >> 3;                // 0..63 (async16 row step)
    const int scol = (tid & 7) * 8;           // shorts
    const int arow = tid >> 4;                // 0..31 (fp32 A row step)
    const int acol4 = (tid & 15) * 4;         // floats

    floatx4 acc[4][4];
#pragma unroll
    for (int i = 0; i < 4; ++i)
#pragma unroll
        for (int j = 0; j < 4; ++j) acc[i][j] = (floatx4){0.f, 0.f, 0.f, 0.f};

    for (int kc = 0; kc < 4; ++kc) {
        const int k0 = kc * 64;
        __syncthreads();
        // stage B: 256 x 64 bf16, 4 async16 passes
#pragma unroll
        for (int i = 0; i < 4; ++i) {
            int rb = i * 64 + srow;
            async16(Bw + (size_t)rb * 256 + k0 + scol, (char*)Bs + i * 8192 + wv * 1024);
        }
        // stage A: 128 x 64
        if (AFP32) {
            const float* A = (const float*)Av;
#pragma unroll
            for (int i = 0; i < 4; ++i) {
                int rr = i * 32 + arow;
                int gr = m0 + rr; gr = gr < M ? gr : M - 1;
                float4 a = *(const float4*)(A + (size_t)gr * 256 + k0 + acol4);
                *(uint2*)&As[rr * 64 + acol4] = make_uint2(pack2(a.x, a.y), pack2(a.z, a.w));
            }
        } else {
            const unsigned short* A = (const unsigned short*)Av;
#pragma unroll
            for (int i = 0; i < 2; ++i) {
                int rr = i * 64 + srow;
                int gr = m0 + rr; gr = gr < M ? gr : M - 1;
                async16(A + (size_t)gr * 256 + k0 + scol, (char*)As + i * 8192 + wv * 1024);
            }
        }
        __syncthreads();
#pragma unroll
        for (int kk = 0; kk < 64; kk += 32) {
            shortx8 af[4], bfr[4];
#pragma unroll
            for (int t = 0; t < 4; ++t) {
                af[t]  = *(const shortx8*)&As[(wm * 64 + t * 16 + lr) * 64 + kk + lq * 8];
                bfr[t] = *(const shortx8*)&Bs[(wn * 64 + t * 16 + lr) * 64 + kk + lq * 8];
            }
#pragma unroll
            for (int ti = 0; ti < 4; ++ti)
#pragma unroll
                for (int tj = 0; tj < 4; ++tj)
                    acc[ti][tj] = __builtin_amdgcn_mfma_f32_16x16x32_bf16(bfr[tj], af[ti], acc[ti][tj], 0, 0, 0);
        }
    }
    // epilogue (transposed D): m = wm*64 + ti*16 + lr, n = wn*64 + tj*16 + lq*4..+3
#pragma unroll
    for (int ti = 0; ti < 4; ++ti) {
        int m = m0 + wm * 64 + ti * 16 + lr;
        if (m >= M) continue;
        if (OUTMODE == 0) {
            float* Crow = (float*)Cv + (size_t)m * 256;
#pragma unroll
            for (int tj = 0; tj < 4; ++tj) {
                int nb = wn * 64 + tj * 16 + lq * 4;
                float4 bv = *(const float4*)(bias + nb);
                *(float4*)(Crow + nb) = make_float4(acc[ti][tj][0] + bv.x, acc[ti][tj][1] + bv.y,
                                                    acc[ti][tj][2] + bv.z, acc[ti][tj][3] + bv.w);
            }
        } else {
            int b = m >= LV ? 1 : 0;
            int lv = m - (b ? LV : 0);
#pragma unroll
            for (int tj = 0; tj < 4; ++tj) {
                int nb = wn * 64 + tj * 16 + lq * 4;
                float4 bv = *(const float4*)(bias + nb);
                int h = nb >> 5, dh = nb & 31;
                unsigned short* dst = (unsigned short*)Cv + ((size_t)(b * 8 + h) * LV + lv) * 32 + dh;
                *(uint2*)dst = make_uint2(pack2(acc[ti][tj][0] + bv.x, acc[ti][tj][1] + bv.y),
                                          pack2(acc[ti][tj][2] + bv.z, acc[ti][tj][3] + bv.w));
            }
        }
    }
}

// ---------------- K2: fp32 tiled GEMM (logits, accuracy-critical) ----------------
__global__ __launch_bounds__(256) void gemm_nt_bias(
    const float* __restrict__ A, const float* __restrict__ W,
    const float* __restrict__ bias, float* __restrict__ C, int M)
{
    const int K = 256, N = 256;
    __shared__ float As[16][68];
    __shared__ float Bs[16][68];
    int tid = threadIdx.x;
    int tcol = tid & 15, trow = tid >> 4;
    int m0 = blockIdx.x * 64, n0 = blockIdx.y * 64;
    int lr = tid >> 2, lc = (tid & 3) << 2;
    float acc[4][4] = {};
    for (int k0 = 0; k0 < K; k0 += 16) {
        int arow = m0 + lr; if (arow > M - 1) arow = M - 1;
        float4 av = *(const float4*)(A + (size_t)arow * K + k0 + lc);
        float4 wv = *(const float4*)(W + (size_t)(n0 + lr) * K + k0 + lc);
        __syncthreads();
        As[lc + 0][lr] = av.x; As[lc + 1][lr] = av.y; As[lc + 2][lr] = av.z; As[lc + 3][lr] = av.w;
        Bs[lc + 0][lr] = wv.x; Bs[lc + 1][lr] = wv.y; Bs[lc + 2][lr] = wv.z; Bs[lc + 3][lr] = wv.w;
        __syncthreads();
#pragma unroll
        for (int k = 0; k < 16; ++k) {
            float4 a4 = *(const float4*)&As[k][trow << 2];
            float4 b4 = *(const float4*)&Bs[k][tcol << 2];
            float a[4] = {a4.x, a4.y, a4.z, a4.w};
            float bb[4] = {b4.x, b4.y, b4.z, b4.w};
#pragma unroll
            for (int i = 0; i < 4; i++)
#pragma unroll
                for (int j = 0; j < 4; j++) acc[i][j] += a[i] * bb[j];
        }
    }
#pragma unroll
    for (int i = 0; i < 4; i++) {
        int m = m0 + trow * 4 + i;
        if (m >= M) continue;
#pragma unroll
        for (int j = 0; j < 4; j++) {
            int n = n0 + tcol * 4 + j;
            C[(size_t)m * N + n] = acc[i][j] + bias[n];
        }
    }
}

// ---------------- K3: XCD-affine fused decode + bilinear gather ----------------
// grid (16, LQ/8): blockIdx.x = slice s = b*8+h (fast dim -> XCD s%8).
__global__ __launch_bounds__(256) void decode_sample_kernel(
    const unsigned short* __restrict__ v,   // bf16 [b*8+h][LV][32]
    const float* __restrict__ logits,       // MQ x 256 (240 real)
    const float* __restrict__ ref_windows,  // MQ x 7
    float* __restrict__ attn_out,           // MQ x 200
    unsigned short* __restrict__ ohbf,      // MQ x 256 bf16
    const int* __restrict__ Hf_p, const int* __restrict__ Wf_p, int LV, int LQ)
{
    __shared__ float lg[8][32];
    __shared__ float rw[8][7];
    __shared__ float prm[8][6];
    __shared__ float mxinv[8][2];
    __shared__ uint4 pk[8][25][2];   // [q][point][colhalf] = {w_row0, w_row1, off0, off1}

    const int s = blockIdx.x, c = blockIdx.y;
    const int b = s >> 3, h = s & 7;
    const int tid = threadIdx.x;
    const int Hf = *Hf_p, Wf = *Wf_p;
    const size_t mbase = (size_t)b * LQ + c * 8;

    if (tid < 240) {
        int qq = tid / 30, j = tid - qq * 30;
        int col = (j < 25) ? h * 25 + j : 200 + h * 5 + (j - 25);
        lg[qq][j] = logits[(mbase + qq) * 256 + col];
    }
    // separate if (NOT else-if): only 256 threads in the block
    if (tid < 56) {
        int qq = tid / 7, k = tid - qq * 7;
        rw[qq][k] = ref_windows[(mbase + qq) * 7 + k];
    }
    __syncthreads();

    if (tid < 8) {
        int qq = tid;
        float mx = -1e30f;
#pragma unroll
        for (int p = 0; p < 25; p++) mx = fmaxf(mx, lg[qq][p]);
        float ssum = 0.f;
#pragma unroll
        for (int p = 0; p < 25; p++) ssum += expf(lg[qq][p] - mx);
        mxinv[qq][0] = mx; mxinv[qq][1] = 1.f / ssum;
        float cx = rw[qq][0] + lg[qq][25] * 0.125f * rw[qq][3];
        float cy = rw[qq][1] + lg[qq][26] * 0.125f * rw[qq][4];
        float bw = rw[qq][3] + lg[qq][27] * 0.125f * rw[qq][3];
        float bh = rw[qq][4] + lg[qq][28] * 0.125f * rw[qq][4];
        float ang = (rw[qq][6] + lg[qq][29] * 0.0625f) * 6.283185307179586f;
        prm[qq][0] = cx; prm[qq][1] = cy;
        prm[qq][2] = fmaxf(bw, 0.f); prm[qq][3] = fmaxf(bh, 0.f);
        prm[qq][4] = cosf(ang); prm[qq][5] = sinf(ang);
    }
    __syncthreads();

    if (tid < 200) {
        int qq = tid / 25, p = tid - qq * 25;
        float a = expf(lg[qq][p] - mxinv[qq][0]) * mxinv[qq][1];
        attn_out[(mbase + qq) * 200 + h * 25 + p] = a;
        int pi = p / 5, pj = p - pi * 5;
        float g0 = (float)(pj - 2) * 0.2f * prm[qq][2];
        float g1 = (float)(pi - 2) * 0.2f * prm[qq][3];
        float ca = prm[qq][4], sa = prm[qq][5];
        float gx = (prm[qq][0] + g0 * ca - g1 * sa) * (float)Wf - 0.5f;
        float gy = (prm[qq][1] + g0 * sa + g1 * ca) * (float)Hf - 0.5f;
        float x0f = floorf(gx), y0f = floorf(gy);
        int x0 = (int)x0f, y0 = (int)y0f;
        float wx1 = gx - x0f, wy1 = gy - y0f;
        float wx0 = 1.f - wx1, wy0 = 1.f - wy1;
        int y1 = y0 + 1;
        int bx; float wl, wr;
        if (x0 >= 0 && x0 <= Wf - 2)      { bx = x0;     wl = wx0; wr = wx1; }
        else if (x0 == -1)                { bx = 0;      wl = wx1; wr = 0.f; }
        else if (x0 == Wf - 1)            { bx = Wf - 2; wl = 0.f; wr = wx0; }
        else                              { bx = 0;      wl = 0.f; wr = 0.f; }
        float wy0v = (y0 >= 0 && y0 < Hf) ? wy0 : 0.f;
        float wy1v = (y1 >= 0 && y1 < Hf) ? wy1 : 0.f;
        int cy0 = min(max(y0, 0), Hf - 1), cy1 = min(max(y1, 0), Hf - 1);
        unsigned off0 = (unsigned)(cy0 * Wf + bx) * 16u;
        unsigned off1 = (unsigned)(cy1 * Wf + bx) * 16u;
        float aw0 = a * wy0v, aw1 = a * wy1v;
        pk[qq][p][0] = make_uint4(__float_as_uint(aw0 * wl), __float_as_uint(aw1 * wl), off0, off1);
        pk[qq][p][1] = make_uint4(__float_as_uint(aw0 * wr), __float_as_uint(aw1 * wr), off0, off1);
    }
    __syncthreads();

    const int qq = tid >> 5, l = tid & 31;
    const unsigned int* vw = (const unsigned int*)(v + (size_t)s * LV * 32);
    const uint4* pkp = &pk[qq][0][l >> 4];
    float e0 = 0.f, o0 = 0.f, e1 = 0.f, o1 = 0.f;
#pragma unroll
    for (int p = 0; p < 25; ++p) {
        uint4 t = pkp[2 * p];                 // ds_read_b128
        float w0 = __uint_as_float(t.x), w1 = __uint_as_float(t.y);
        unsigned u0 = vw[t.z + l];
        unsigned u1 = vw[t.w + l];
        e0 += w0 * __uint_as_float(u0 << 16);
        o0 += w0 * __uint_as_float(u0 & 0xffff0000u);
        e1 += w1 * __uint_as_float(u1 << 16);
        o1 += w1 * __uint_as_float(u1 & 0xffff0000u);
    }
    float a0 = e0 + e1, a1 = o0 + o1;
    a0 += __shfl_xor(a0, 16, 32);
    a1 += __shfl_xor(a1, 16, 32);
    if (l < 16)
        ((unsigned int*)ohbf)[(mbase + qq) * 128 + h * 16 + l] = pack2(a0, a1);
}

extern "C" void kernel_launch(void* const* d_in, const int* in_sizes, int n_in,
                              void* d_out, int out_size, void* d_ws, size_t ws_size,
                              hipStream_t stream) {
    const float* query       = (const float*)d_in[0];
    const float* value       = (const float*)d_in[1];
    const float* ref_windows = (const float*)d_in[2];
    const float* W_box       = (const float*)d_in[3];
    const float* b_box       = (const float*)d_in[4];
    const float* W_attn      = (const float*)d_in[5];
    const float* b_attn      = (const float*)d_in[6];
    const float* W_value     = (const float*)d_in[7];
    const float* b_value     = (const float*)d_in[8];
    const float* W_out       = (const float*)d_in[9];
    const float* b_out       = (const float*)d_in[10];
    const int*   Hf          = (const int*)d_in[11];
    const int*   Wf          = (const int*)d_in[12];

    const int M1 = in_sizes[1] / 256;  // B*LV = 70688
    const int MQ = in_sizes[0] / 256;  // B*LQ = 8192
    const int LQ = MQ / 2;
    const int LV = M1 / 2;

    unsigned short* Vout = (unsigned short*)d_ws;                 // M1*256
    unsigned short* ohbf = Vout + (size_t)M1 * 256;               // MQ*256
    unsigned short* wvbf = ohbf + (size_t)MQ * 256;               // 65536
    unsigned short* wabf = wvbf + 65536;                          // 65536
    unsigned short* wobf = wabf + 65536;                          // 65536
    float* Wab       = (float*)(wobf + 65536);                    // 65536 fp32
    float* bab       = Wab + 65536;                               // 256
    float* logits    = bab + 256;                                 // MQ*256

    float* out0     = (float*)d_out;
    float* attn_out = out0 + (size_t)MQ * 256;

    // K0: weight conversions
    convert_w<<<49, 256, 0, stream>>>(W_value, wvbf, W_attn, W_box, wabf, Wab,
                                      W_out, wobf, b_attn, b_box, bab);
    // K1: value projection (fp32 A fused-converted) -> head-major bf16 Vout
    gemm_mfma<1, 1><<<(M1 + 127) / 128, 512, 0, stream>>>(value, wvbf, b_value, Vout, M1, LV);
    // K2: logits fp32 (accuracy-critical box path)
    dim3 g2(MQ / 64, 4);
    gemm_nt_bias<<<g2, 256, 0, stream>>>(query, Wab, bab, logits, MQ);
    // K3: XCD-affine fused softmax + box decode + gather -> bf16 out_heads
    decode_sample_kernel<<<dim3(16, LQ / 8), 256, 0, stream>>>(
        Vout, logits, ref_windows, attn_out, ohbf, Hf, Wf, LV, LQ);
    // K4: output projection (bf16 A via async16)
    gemm_mfma<0, 0><<<MQ / 128, 512, 0, stream>>>(ohbf, wobf, b_out, out0, MQ, LV);
}